// Round 4
// baseline (301.848 us; speedup 1.0000x reference)
//
#include <hip/hip_runtime.h>
#include <cstdint>
#include <cstddef>

// ---------------------------------------------------------------------------
// Conv2d 3x3 s1 p1 on 16-bit fixed-point (12 frac bits) quantized operands.
// x: (32,128,56,56) f32   w: (256,128,3,3) f32   out: (32,256,56,56) f32
// Implicit GEMM M=256, N=100352, K=1152.
// 256x256 tile, BK=64, 512 thr / 8 waves, XCD swizzle (392 = 8*49).
// R4: A (weights, 576 KiB, L2-resident) is loaded DIRECTLY from global into
// registers (8x global_load_dwordx4 per wave per kt) — no A LDS staging and
// no A ds_reads. LDS holds only B (x-pixels): 2 buffers x 32 KiB, XOR-8
// chunk swizzle. This removes ~2/3 of the LDS-port traffic that co-limited
// the kernel at 2 waves/SIMD (unified VGPR+AGPR ~252/256 caps occupancy).
// Counted-vmcnt pipeline: A(kt+1) prefetch + B(kt+2) stage stay in flight
// across each K-step; never a fresh drain in the loop.
// ---------------------------------------------------------------------------

typedef __attribute__((ext_vector_type(8))) short short8;
typedef __attribute__((ext_vector_type(4))) float floatx4;

#define NIMG 32
#define CIN  128
#define HW   56
#define KOUT 256
#define HP   58                                   // padded H/W
#define XPAD_ELEMS ((size_t)NIMG * HP * HP * CIN) // 13,778,944
#define WT_OFF_BYTES (XPAD_ELEMS * 2)             // 27,557,888 (256B aligned)
#define KK 1152

__device__ __forceinline__ uint16_t quant_bf16(float v) {
    // round-half-even to 12 frac bits, clip to int16 range, then RNE to bf16
    float q = rintf(v * 4096.0f);
    q = fminf(fmaxf(q, -32768.0f), 32767.0f) * (1.0f / 4096.0f);
    union { float f; uint32_t u; } cv; cv.f = q;
    uint32_t u = cv.u;
    return (uint16_t)((u + 0x7fffu + ((u >> 16) & 1u)) >> 16);
}

// ---- transform x: NCHW f32 -> padded NHWC bf16 [32][58][58][128] ----------
__global__ __launch_bounds__(256) void quant_pad_x(const float* __restrict__ x,
                                                   uint16_t* __restrict__ xp) {
    const int b = blockIdx.x;            // one padded row (n, hp) each
    const int n = b / HP, hp = b - n * HP;
    uint16_t* row = xp + (size_t)(n * HP + hp) * HP * CIN;

    if (hp == 0 || hp == HP - 1) {       // top/bottom pad row: all zeros
        uint4 z{0, 0, 0, 0};
        uint4* d = (uint4*)row;
        for (int t = threadIdx.x; t < HP * CIN * 2 / 16; t += 256) d[t] = z;
        return;
    }
    const int h = hp - 1;
    __shared__ uint16_t tile[HW * 130];  // [w][c], +2 pad breaks bank conflicts
    const float* src = x + (size_t)n * CIN * HW * HW + (size_t)h * HW;
    for (int t = threadIdx.x; t < CIN * 14; t += 256) {      // float4 loads
        int c = t / 14, w4 = t - c * 14;
        float4 v = *(const float4*)(src + (size_t)c * (HW * HW) + w4 * 4);
        int base = (w4 * 4) * 130 + c;
        tile[base]       = quant_bf16(v.x);
        tile[base + 130] = quant_bf16(v.y);
        tile[base + 260] = quant_bf16(v.z);
        tile[base + 390] = quant_bf16(v.w);
    }
    __syncthreads();
    if (threadIdx.x < 32) {              // zero left/right pad pixels
        uint4 z{0, 0, 0, 0};
        if (threadIdx.x < 16) ((uint4*)row)[threadIdx.x] = z;
        else ((uint4*)(row + 57 * CIN))[threadIdx.x - 16] = z;
    }
    uint2* dst = (uint2*)(row + CIN);    // interior cols 1..56, 8B stores
    for (int t = threadIdx.x; t < (HW * CIN) / 4; t += 256) {
        int w = t >> 5, c4 = (t & 31) * 4;
        uint32_t a = tile[w * 130 + c4]     | ((uint32_t)tile[w * 130 + c4 + 1] << 16);
        uint32_t c = tile[w * 130 + c4 + 2] | ((uint32_t)tile[w * 130 + c4 + 3] << 16);
        dst[t] = make_uint2(a, c);
    }
}

// ---- transform w: OIHW f32 -> Wt[k][tap*128+c] bf16 ------------------------
__global__ __launch_bounds__(256) void quant_w(const float* __restrict__ w,
                                               uint16_t* __restrict__ wt) {
    int i = blockIdx.x * 256 + threadIdx.x;   // 256*1152 = 294912 exact
    int k = i / KK;
    int r = i - k * KK;
    int tap = r >> 7;          // 0..8
    int c = r & 127;
    wt[i] = quant_bf16(w[(size_t)(k * CIN + c) * 9 + tap]);
}

// ---- main implicit GEMM ----------------------------------------------------
// LDS: ldsB[buf][half][128*64] bf16 only (buf0 = even kt, buf1 = odd kt).
// Row = 128B = 8 chunks of 16B; slot s at row r holds data chunk s^(r&7)
// (staged via pre-swizzled GLOBAL source, gload_lds dest stays linear).
// A comes straight from L2: per kt, 8 global_load_dwordx4 per wave into ra.
//
// Per K-step kt (buf b = kt&1), issue order per wave:
//   READ_B rb0, rb1              (8 ds_read_b128)
//   MFMA (0,0) (0,1)             (ra = A(kt,q4=0); compiler waits vmcnt(4):
//                                 the 4 newer B-stages stay in flight)
//   LOAD_A(kt, q4=1) -> ra       (8 gloads, hidden under the MFMA above)
//   MFMA (1,0) (1,1)
//   barrier                      (all waves done reading ldsB[b])
//   LOAD_A(kt+1, q4=0) -> ra     (prefetch; in flight across barrier+stage)
//   STAGE_B(b, kt+2)             (4 gloads)
//   vmcnt(12)                    (12 = 8 A-prefetch + 4 fresh stages; proves
//                                 B(kt+1), issued one kt ago, has landed)
//   barrier
// Never a fresh-drain vmcnt in the loop.

#define GLOAD(gsrc, ldst)                                                      \
    __builtin_amdgcn_global_load_lds(                                          \
        (__attribute__((address_space(1))) void*)(void*)(gsrc),                \
        (__attribute__((address_space(3))) void*)(void*)(ldst), 16, 0, 0)

#define STAGE_B(bsel, kt) do {                                                 \
    const int tap_ = (kt) >> 1;                                                \
    const size_t boff_ = (size_t)((tap_ / 3) * HP + (tap_ % 3)) * CIN          \
                       + (size_t)((kt) & 1) * 64;                              \
    GLOAD(bGp[0][0] + boff_, &ldsB[bsel][0][(wv * 8) * 64]);                   \
    GLOAD(bGp[0][1] + boff_, &ldsB[bsel][0][(64 + wv * 8) * 64]);              \
    GLOAD(bGp[1][0] + boff_, &ldsB[bsel][1][(wv * 8) * 64]);                   \
    GLOAD(bGp[1][1] + boff_, &ldsB[bsel][1][(64 + wv * 8) * 64]);              \
} while (0)

// A fragments direct from global (L2-resident weights). Same (row,k) mapping
// as the old LDS path: row = wm*128 + q4*64 + f*16 + m16, k = kt*64+s*32+q*8.
#define LOAD_A(q4, kt) do {                                                    \
    const uint16_t* ab_ = aB + (kt) * 64;                                      \
    _Pragma("unroll")                                                          \
    for (int f_ = 0; f_ < 4; ++f_) {                                           \
        ra[f_][0] = *(const short8*)(ab_ + ((q4) * 64 + f_ * 16) * KK);        \
        ra[f_][1] = *(const short8*)(ab_ + ((q4) * 64 + f_ * 16) * KK + 32);   \
    }                                                                          \
} while (0)

#define READ_B(dst, bsel, ch) do {                                             \
    _Pragma("unroll")                                                          \
    for (int fc_ = 0; fc_ < 2; ++fc_) {                                        \
        const int r_ = bl + (ch) * 32 + fc_ * 16 + m16;                        \
        dst[fc_][0] = *(const short8*)&ldsB[bsel][bh][r_ * 64 + sl0];          \
        dst[fc_][1] = *(const short8*)&ldsB[bsel][bh][r_ * 64 + sl1];          \
    }                                                                          \
} while (0)

#define MFMA_Q(q4, ch, B) do {                                                 \
    _Pragma("unroll")                                                          \
    for (int s_ = 0; s_ < 2; ++s_)                                             \
    _Pragma("unroll")                                                          \
    for (int f_ = 0; f_ < 4; ++f_)                                             \
    _Pragma("unroll")                                                          \
    for (int c_ = 0; c_ < 2; ++c_)                                             \
        acc[q4][f_][ch][c_] = __builtin_amdgcn_mfma_f32_16x16x32_bf16(         \
            ra[f_][s_], B[c_][s_], acc[q4][f_][ch][c_], 0, 0, 0);              \
} while (0)

#define KT_BODY(bsel, kt) do {                                                 \
    READ_B(rb0, bsel, 0);                                                      \
    READ_B(rb1, bsel, 1);                                                      \
    __builtin_amdgcn_s_setprio(1);                                             \
    MFMA_Q(0, 0, rb0);                                                         \
    MFMA_Q(0, 1, rb1);                                                         \
    __builtin_amdgcn_s_setprio(0);                                             \
    LOAD_A(1, kt);                   /* hidden under the MFMA cluster above */ \
    __builtin_amdgcn_s_setprio(1);                                             \
    MFMA_Q(1, 0, rb0);                                                         \
    MFMA_Q(1, 1, rb1);                                                         \
    __builtin_amdgcn_s_setprio(0);                                             \
} while (0)

#define KT_TAIL(bsel, ktp1, ktp2) do {                                         \
    __builtin_amdgcn_s_barrier();                                              \
    LOAD_A(0, ktp1);                 /* A prefetch BEFORE stage: compiler's */ \
    STAGE_B(bsel, ktp2);             /* wait for ra is vmcnt(4), not 0      */ \
    asm volatile("s_waitcnt vmcnt(12)" ::: "memory");                          \
    __builtin_amdgcn_s_barrier();                                              \
} while (0)

__global__ __launch_bounds__(512, 2) void conv_gemm(const uint16_t* __restrict__ xp,
                                                    const uint16_t* __restrict__ wt,
                                                    float* __restrict__ out) {
    __shared__ __align__(16) uint16_t ldsB[2][2][128 * 64];   // 64 KiB (B only)

    const int tid  = threadIdx.x;
    const int l    = tid & 63;
    const int wv   = tid >> 6;        // 0..7
    const int wm   = wv >> 2;         // 0..1: kout half this wave computes
    const int wn   = wv & 3;          // 0..3: px quarter
    const int bh   = wn >> 1;         // B half this wave reads
    const int bl   = (wn & 1) * 64;   // local px base within B half
    const int srow = l >> 3;          // 0..7
    const int c_data = (l & 7) ^ srow;    // swizzled source chunk (B staging)
    const int m16  = l & 15;
    const int q    = l >> 4;          // 0..3
    const int r7   = m16 & 7;
    const int sl0  = ((0 + q) ^ r7) * 8;  // B read slot, k-half 0 (elements)
    const int sl1  = ((4 + q) ^ r7) * 8;  // B read slot, k-half 1

    const int b = blockIdx.x;                      // 0..391
    const int pxblk = (b & 7) * 49 + (b >> 3);     // XCD swizzle, 392 = 8*49

    // Per-lane A base: row wm*128 + m16, k chunk q*8 (direct-L2 operand).
    const uint16_t* aB = wt + (size_t)((wm * 128 + m16) * KK + q * 8);

    // Per-lane global staging base pointers for B (fixed across K loop).
    const uint16_t* bGp[2][2];
#pragma unroll
    for (int h_ = 0; h_ < 2; ++h_)
#pragma unroll
        for (int j_ = 0; j_ < 2; ++j_) {
            const int row = h_ * 128 + j_ * 64 + wv * 8 + srow;   // 0..255
            const int p = pxblk * 256 + row;                      // global px
            const int n = p / 3136; const int rem = p - n * 3136;
            const int hh = rem / HW; const int ww = rem - hh * HW;
            bGp[h_][j_] = xp + (size_t)((n * HP + hh) * HP + ww) * CIN + c_data * 8;
        }

    floatx4 acc[2][4][2][2];
#pragma unroll
    for (int a_ = 0; a_ < 2; ++a_)
#pragma unroll
        for (int f_ = 0; f_ < 4; ++f_)
#pragma unroll
            for (int c_ = 0; c_ < 2; ++c_)
#pragma unroll
                for (int d_ = 0; d_ < 2; ++d_)
                    acc[a_][f_][c_][d_] = (floatx4){0.f, 0.f, 0.f, 0.f};

    short8 ra[4][2];          // A frags for the active row-half (q4)
    short8 rb0[2][2];         // B frags ch=0
    short8 rb1[2][2];         // B frags ch=1

    // ---- prologue: A(0,q4=0) to regs; stage B(0)->buf0, B(1)->buf1.
    // vmcnt(4): A + B(0) landed, B(1)'s 4 loads may stay in flight.
    LOAD_A(0, 0);
    STAGE_B(0, 0);
    STAGE_B(1, 1);
    asm volatile("s_waitcnt vmcnt(4)" ::: "memory");
    __builtin_amdgcn_s_barrier();

#pragma unroll 1
    for (int it = 0; it < 8; ++it) {
        const int kt0 = 2 * it;
        KT_BODY(0, kt0);                 // kt even  (buf0)
        KT_TAIL(0, kt0 + 1, kt0 + 2);    // prefetch A(kt+1), stage B(kt+2)
        KT_BODY(1, kt0 + 1);             // kt odd   (buf1)
        KT_TAIL(1, kt0 + 2, kt0 + 3);    // prefetch A(kt+2), stage B(kt+3)
    }

    // ---- tail: kt16 (buf0), kt17 (buf1) — no more staging
    KT_BODY(0, 16);
    __builtin_amdgcn_s_barrier();
    LOAD_A(0, 17);
    asm volatile("s_waitcnt vmcnt(8)" ::: "memory");   // B(17) proven landed
    __builtin_amdgcn_s_barrier();
    KT_BODY(1, 17);

    // ---- epilogue: D row = kout (quad*4+reg), col = px (lane&15).
    // fc (the two 64B halves of each 128B line) innermost so the line is
    // completed by adjacent store instructions (write-combine friendly).
#pragma unroll
    for (int ch = 0; ch < 2; ++ch) {
        const int p0 = pxblk * 256 + wn * 64 + ch * 32 + m16;
        const int n = p0 / 3136; const int rem0 = p0 - n * 3136;   // fc=0 px
        float* opb = out + (size_t)(n * KOUT + wm * 128) * 3136 + rem0;
#pragma unroll
        for (int q4 = 0; q4 < 2; ++q4)
#pragma unroll
            for (int f = 0; f < 4; ++f) {
                const int kl = q4 * 64 + f * 16 + q * 4;
#pragma unroll
                for (int t = 0; t < 4; ++t) {
                    float* op = opb + (size_t)(kl + t) * 3136;
                    op[0]  = acc[q4][f][ch][0][t];
                    op[16] = acc[q4][f][ch][1][t];
                }
            }
    }
}

extern "C" void kernel_launch(void* const* d_in, const int* in_sizes, int n_in,
                              void* d_out, int out_size, void* d_ws, size_t ws_size,
                              hipStream_t stream) {
    const float* x = (const float*)d_in[0];
    const float* w = (const float*)d_in[1];
    float* out = (float*)d_out;

    uint16_t* xp  = (uint16_t*)d_ws;                           // 27.56 MB padded bf16 x
    uint16_t* wtb = (uint16_t*)((char*)d_ws + WT_OFF_BYTES);   // 0.59 MB bf16 weights

    quant_pad_x<<<NIMG * HP, 256, 0, stream>>>(x, xp);         // covers ALL of xp incl. borders
    quant_w<<<(KOUT * KK) / 256, 256, 0, stream>>>(w, wtb);

    conv_gemm<<<dim3(392), dim3(512), 0, stream>>>(xp, wtb, out);
}

// Round 5
// 208.558 us; speedup vs baseline: 1.4473x; 1.4473x over previous
//
#include <hip/hip_runtime.h>
#include <cstdint>
#include <cstddef>

// ---------------------------------------------------------------------------
// Conv2d 3x3 s1 p1 on 16-bit fixed-point (12 frac bits) quantized operands.
// x: (32,128,56,56) f32   w: (256,128,3,3) f32   out: (32,256,56,56) f32
// Implicit GEMM M=256, N=100352, K=1152.
// conv_gemm = R3 structure verbatim (82.3 us proven): 256x256 tile, BK=64,
// 512 thr / 8 waves, coarse 2-barrier K-step, counted vmcnt(8), XOR-8 chunk
// swizzle, XCD swizzle.
// R5 changes (layout only, no sync-structure change):
//  * Weights stored kt-major: wt2[kt][row][64]. Each A-staging gload_lds now
//    reads a contiguous (permuted) 1KB window -> ~4x fewer L2 requests.
//    LDS contents are bit-identical to R3 (slab row = same 64 consecutive kk).
//  * quant_pad_x uses b64 LDS writes / b128 LDS reads (4x wider, ~4x fewer
//    LDS ops) and 16B global stores.
// ---------------------------------------------------------------------------

typedef __attribute__((ext_vector_type(8))) short short8;
typedef __attribute__((ext_vector_type(4))) float floatx4;

#define NIMG 32
#define CIN  128
#define HW   56
#define KOUT 256
#define HP   58                                   // padded H/W
#define XPAD_ELEMS ((size_t)NIMG * HP * HP * CIN) // 13,778,944
#define WT_OFF_BYTES (XPAD_ELEMS * 2)             // 27,557,888 (256B aligned)
#define KK 1152

__device__ __forceinline__ uint16_t quant_bf16(float v) {
    // round-half-even to 12 frac bits, clip to int16 range, then RNE to bf16
    float q = rintf(v * 4096.0f);
    q = fminf(fmaxf(q, -32768.0f), 32767.0f) * (1.0f / 4096.0f);
    union { float f; uint32_t u; } cv; cv.f = q;
    uint32_t u = cv.u;
    return (uint16_t)((u + 0x7fffu + ((u >> 16) & 1u)) >> 16);
}

__device__ __forceinline__ float f4c(float4 v, int k) {
    switch (k) { case 0: return v.x; case 1: return v.y;
                 case 2: return v.z; default: return v.w; }
}

// ---- transform x: NCHW f32 -> padded NHWC bf16 [32][58][58][128] ----------
// LDS tile stride 136 elems (272B): 8B-aligned b64 writes, 16B-aligned b128
// reads, bank stride 68%32=4 (conflict-mild).
__global__ __launch_bounds__(256) void quant_pad_x(const float* __restrict__ x,
                                                   uint16_t* __restrict__ xp) {
    const int b = blockIdx.x;            // one padded row (n, hp) each
    const int n = b / HP, hp = b - n * HP;
    uint16_t* row = xp + (size_t)(n * HP + hp) * HP * CIN;

    if (hp == 0 || hp == HP - 1) {       // top/bottom pad row: all zeros
        uint4 z{0, 0, 0, 0};
        uint4* d = (uint4*)row;
        for (int t = threadIdx.x; t < HP * CIN * 2 / 16; t += 256) d[t] = z;
        return;
    }
    const int h = hp - 1;
    __shared__ __align__(16) uint16_t tile[HW * 136];  // [w][c] stride 136
    const float* src = x + (size_t)n * CIN * HW * HW + (size_t)h * HW;
    // 32 channel-groups of 4 x 14 w4-groups = 448 tasks; 4 float4 loads each,
    // pack 4 channels -> one ds_write_b64 per output pixel (4 per task).
    for (int t = threadIdx.x; t < 32 * 14; t += 256) {
        int cg = t / 14, w4 = t - cg * 14;
        int c4 = cg * 4;
        float4 v0 = *(const float4*)(src + (size_t)(c4 + 0) * (HW * HW) + w4 * 4);
        float4 v1 = *(const float4*)(src + (size_t)(c4 + 1) * (HW * HW) + w4 * 4);
        float4 v2 = *(const float4*)(src + (size_t)(c4 + 2) * (HW * HW) + w4 * 4);
        float4 v3 = *(const float4*)(src + (size_t)(c4 + 3) * (HW * HW) + w4 * 4);
#pragma unroll
        for (int k = 0; k < 4; ++k) {
            int w = w4 * 4 + k;
            uint32_t lo = (uint32_t)quant_bf16(f4c(v0, k)) |
                          ((uint32_t)quant_bf16(f4c(v1, k)) << 16);
            uint32_t hi = (uint32_t)quant_bf16(f4c(v2, k)) |
                          ((uint32_t)quant_bf16(f4c(v3, k)) << 16);
            *(uint2*)&tile[w * 136 + c4] = make_uint2(lo, hi);
        }
    }
    __syncthreads();
    if (threadIdx.x < 32) {              // zero left/right pad pixels
        uint4 z{0, 0, 0, 0};
        if (threadIdx.x < 16) ((uint4*)row)[threadIdx.x] = z;
        else ((uint4*)(row + 57 * CIN))[threadIdx.x - 16] = z;
    }
    // interior cols 1..56: b128 LDS reads, 16B global stores
    uint4* dst = (uint4*)(row + CIN);    // 56*128/8 = 896 uint4s
    for (int t = threadIdx.x; t < HW * 16; t += 256) {
        int w = t >> 4, c8 = (t & 15) * 8;
        dst[t] = *(const uint4*)&tile[w * 136 + c8];
    }
}

// ---- transform w: OIHW f32 -> kt-major Wt2[kt][k_out 0..255][64] bf16 ------
// Slab kt (0..17) holds kk = kt*64 .. kt*64+63 for every output channel:
// kk = tap*128 + c  with  tap = kt>>1, c = (kt&1)*64 + j  (j = kk - kt*64).
__global__ __launch_bounds__(256) void quant_w(const float* __restrict__ w,
                                               uint16_t* __restrict__ wt) {
    int i = blockIdx.x * 256 + threadIdx.x;   // 256*1152 = 294912 exact
    int kt = i >> 14;            // / 16384
    int rem = i & 16383;
    int r = rem >> 6;            // k_out 0..255
    int j = rem & 63;
    int tap = kt >> 1;
    int c = ((kt & 1) << 6) + j;
    wt[i] = quant_bf16(w[(size_t)(r * CIN + c) * 9 + tap]);
}

// ---- main implicit GEMM ----------------------------------------------------
// LDS: ldsA/ldsB[buf][half][128*64] bf16 (buf0 = even kt, buf1 = odd kt).
// Row = 128B = 8 chunks of 16B; slot s at row r holds data chunk s^(r&7)
// (staged via pre-swizzled GLOBAL source, gload_lds dest stays linear).
//
// Per K-step kt (buffer stable, no internal barriers):
//   reads ra(q4=0), rb0, rb1  (16 ds_read_b128)
//   MFMA quads (0,0), (0,1)
//   reads ra(q4=1)            (8 ds_read_b128, WAR-reuse of ra regs)
//   MFMA quads (1,0), (1,1)
//   barrier                   // all waves done READING this buffer
//   STAGE kt+2 into it        (8 global_load_lds)
//   vmcnt(8)                  // kt+1's loads (issued one full kt ago) landed
//   barrier                   // kt+1 buffer visible to all waves
// Never a fresh-drain vmcnt in the loop; staging spans an entire K-step.

#define GLOAD(gsrc, ldst)                                                      \
    __builtin_amdgcn_global_load_lds(                                          \
        (__attribute__((address_space(1))) void*)(void*)(gsrc),                \
        (__attribute__((address_space(3))) void*)(void*)(ldst), 16, 0, 0)

// kt-major weights: slab base wt + kt*16384; lane offset a00 (+h*8192+jj*4096)
// -> each gload's 64 lanes cover one contiguous (permuted) 1KB window.
#define STAGE_A(bsel, kt) do {                                                 \
    const uint16_t* as_ = wt + (size_t)(kt) * 16384 + a00;                     \
    GLOAD(as_,         &ldsA[bsel][0][(wv * 8) * 64]);                         \
    GLOAD(as_ + 4096,  &ldsA[bsel][0][(64 + wv * 8) * 64]);                    \
    GLOAD(as_ + 8192,  &ldsA[bsel][1][(wv * 8) * 64]);                         \
    GLOAD(as_ + 12288, &ldsA[bsel][1][(64 + wv * 8) * 64]);                    \
} while (0)

#define STAGE_B(bsel, kt) do {                                                 \
    const int tap_ = (kt) >> 1;                                                \
    const size_t boff_ = (size_t)((tap_ / 3) * HP + (tap_ % 3)) * CIN          \
                       + (size_t)((kt) & 1) * 64;                              \
    GLOAD(bGp[0][0] + boff_, &ldsB[bsel][0][(wv * 8) * 64]);                   \
    GLOAD(bGp[0][1] + boff_, &ldsB[bsel][0][(64 + wv * 8) * 64]);              \
    GLOAD(bGp[1][0] + boff_, &ldsB[bsel][1][(wv * 8) * 64]);                   \
    GLOAD(bGp[1][1] + boff_, &ldsB[bsel][1][(64 + wv * 8) * 64]);              \
} while (0)

#define READ_A(bsel, q4) do {                                                  \
    _Pragma("unroll")                                                          \
    for (int f_ = 0; f_ < 4; ++f_) {                                           \
        const int r_ = (q4) * 64 + f_ * 16 + m16;                              \
        ra[f_][0] = *(const short8*)&ldsA[bsel][wm][r_ * 64 + sl0];            \
        ra[f_][1] = *(const short8*)&ldsA[bsel][wm][r_ * 64 + sl1];            \
    }                                                                          \
} while (0)

#define READ_B(dst, bsel, ch) do {                                             \
    _Pragma("unroll")                                                          \
    for (int fc_ = 0; fc_ < 2; ++fc_) {                                        \
        const int r_ = bl + (ch) * 32 + fc_ * 16 + m16;                        \
        dst[fc_][0] = *(const short8*)&ldsB[bsel][bh][r_ * 64 + sl0];          \
        dst[fc_][1] = *(const short8*)&ldsB[bsel][bh][r_ * 64 + sl1];          \
    }                                                                          \
} while (0)

#define MFMA_Q(q4, ch, B) do {                                                 \
    _Pragma("unroll")                                                          \
    for (int s_ = 0; s_ < 2; ++s_)                                             \
    _Pragma("unroll")                                                          \
    for (int f_ = 0; f_ < 4; ++f_)                                             \
    _Pragma("unroll")                                                          \
    for (int c_ = 0; c_ < 2; ++c_)                                             \
        acc[q4][f_][ch][c_] = __builtin_amdgcn_mfma_f32_16x16x32_bf16(         \
            ra[f_][s_], B[c_][s_], acc[q4][f_][ch][c_], 0, 0, 0);              \
} while (0)

// One full K-step of compute on buffer bsel. No barriers inside: the compiler
// interleaves ds_read/lgkmcnt with the MFMA clusters (fine-grained waits),
// and co-resident waves drift to overlap LDS port vs matrix pipe.
#define KT_BODY(bsel) do {                                                     \
    READ_A(bsel, 0);                                                           \
    READ_B(rb0, bsel, 0);                                                      \
    READ_B(rb1, bsel, 1);                                                      \
    __builtin_amdgcn_s_setprio(1);                                             \
    MFMA_Q(0, 0, rb0);                                                         \
    MFMA_Q(0, 1, rb1);                                                         \
    __builtin_amdgcn_s_setprio(0);                                             \
    READ_A(bsel, 1);                 /* WAR reuse of ra: after (0,*) issued */  \
    __builtin_amdgcn_s_setprio(1);                                             \
    MFMA_Q(1, 0, rb0);                                                         \
    MFMA_Q(1, 1, rb1);                                                         \
    __builtin_amdgcn_s_setprio(0);                                             \
} while (0)

// End-of-K-step sync + prefetch: overwrite-safety barrier, stage kt+2 into the
// buffer just consumed, counted wait for kt+1 (issued one K-step ago), then
// visibility barrier for kt+1.
#define KT_SYNC_STAGE(bsel, ktn) do {                                          \
    __builtin_amdgcn_s_barrier();                                              \
    STAGE_A(bsel, ktn); STAGE_B(bsel, ktn);                                    \
    asm volatile("s_waitcnt vmcnt(8)" ::: "memory");                           \
    __builtin_amdgcn_s_barrier();                                              \
} while (0)

__global__ __launch_bounds__(512, 2) void conv_gemm(const uint16_t* __restrict__ xp,
                                                    const uint16_t* __restrict__ wt,
                                                    float* __restrict__ out) {
    __shared__ __align__(16) uint16_t ldsA[2][2][128 * 64];   // 64 KiB
    __shared__ __align__(16) uint16_t ldsB[2][2][128 * 64];   // 64 KiB

    const int tid  = threadIdx.x;
    const int l    = tid & 63;
    const int wv   = tid >> 6;        // 0..7
    const int wm   = wv >> 2;         // 0..1: kout half (wave reads A-half wm)
    const int wn   = wv & 3;          // 0..3: px quarter
    const int bh   = wn >> 1;         // B half this wave reads
    const int bl   = (wn & 1) * 64;   // local px base within B half
    const int srow = l >> 3;          // 0..7
    const int c_data = (l & 7) ^ srow;    // swizzled source chunk
    const int m16  = l & 15;
    const int q    = l >> 4;          // 0..3
    const int r7   = m16 & 7;
    const int sl0  = ((0 + q) ^ r7) * 8;  // read slot, k-half 0 (elements)
    const int sl1  = ((4 + q) ^ r7) * 8;  // read slot, k-half 1

    const int b = blockIdx.x;                      // 0..391
    const int pxblk = (b & 7) * 49 + (b >> 3);     // XCD swizzle, 392 = 8*49

    // Per-lane A source offset within a kt slab: row = wv*8+srow (+64*jj,
    // +128*h as compile-time adds in STAGE_A), chunk c_data.
    const int a00 = (wv * 8 + srow) * 64 + c_data * 8;

    // Per-lane global staging base pointers for B (fixed across K loop).
    const uint16_t* bGp[2][2];
#pragma unroll
    for (int h_ = 0; h_ < 2; ++h_)
#pragma unroll
        for (int j_ = 0; j_ < 2; ++j_) {
            const int row = h_ * 128 + j_ * 64 + wv * 8 + srow;   // 0..255
            const int p = pxblk * 256 + row;                      // global px
            const int n = p / 3136; const int rem = p - n * 3136;
            const int hh = rem / HW; const int ww = rem - hh * HW;
            bGp[h_][j_] = xp + (size_t)((n * HP + hh) * HP + ww) * CIN + c_data * 8;
        }

    floatx4 acc[2][4][2][2];
#pragma unroll
    for (int a_ = 0; a_ < 2; ++a_)
#pragma unroll
        for (int f_ = 0; f_ < 4; ++f_)
#pragma unroll
            for (int c_ = 0; c_ < 2; ++c_)
#pragma unroll
                for (int d_ = 0; d_ < 2; ++d_)
                    acc[a_][f_][c_][d_] = (floatx4){0.f, 0.f, 0.f, 0.f};

    short8 ra[4][2];          // A frags for the active row-half (q4)
    short8 rb0[2][2];         // B frags ch=0
    short8 rb1[2][2];         // B frags ch=1

    // ---- prologue: stage kt0 -> buf0, kt1 -> buf1; only kt1 may stay in flight
    STAGE_A(0, 0); STAGE_B(0, 0);
    STAGE_A(1, 1); STAGE_B(1, 1);
    asm volatile("s_waitcnt vmcnt(8)" ::: "memory");
    __builtin_amdgcn_s_barrier();

#pragma unroll 1
    for (int it = 0; it < 8; ++it) {
        const int ktE = 2 * it + 2;
        const int ktO = 2 * it + 3;
        KT_BODY(0);                     // kt = 2it   (buf0)
        KT_SYNC_STAGE(0, ktE);          // stage kt+2, confirm kt+1
        KT_BODY(1);                     // kt = 2it+1 (buf1)
        KT_SYNC_STAGE(1, ktO);          // stage kt+3, confirm kt+2
    }

    // ---- tail: kt16 (buf0), kt17 (buf1) — no staging
    KT_BODY(0);
    __builtin_amdgcn_s_barrier();
    asm volatile("s_waitcnt vmcnt(0)" ::: "memory");   // kt17 (issued long ago) landed
    __builtin_amdgcn_s_barrier();
    KT_BODY(1);

    // ---- epilogue: D row = kout (quad*4+reg), col = px (lane&15).
    // fc (the two 64B halves of each 128B line) innermost so the line is
    // completed by adjacent store instructions (write-combine friendly).
#pragma unroll
    for (int ch = 0; ch < 2; ++ch) {
        const int p0 = pxblk * 256 + wn * 64 + ch * 32 + m16;
        const int n = p0 / 3136; const int rem0 = p0 - n * 3136;   // fc=0 px
        float* opb = out + (size_t)(n * KOUT + wm * 128) * 3136 + rem0;
#pragma unroll
        for (int q4 = 0; q4 < 2; ++q4)
#pragma unroll
            for (int f = 0; f < 4; ++f) {
                const int kl = q4 * 64 + f * 16 + q * 4;
#pragma unroll
                for (int t = 0; t < 4; ++t) {
                    float* op = opb + (size_t)(kl + t) * 3136;
                    op[0]  = acc[q4][f][ch][0][t];
                    op[16] = acc[q4][f][ch][1][t];
                }
            }
    }
}

extern "C" void kernel_launch(void* const* d_in, const int* in_sizes, int n_in,
                              void* d_out, int out_size, void* d_ws, size_t ws_size,
                              hipStream_t stream) {
    const float* x = (const float*)d_in[0];
    const float* w = (const float*)d_in[1];
    float* out = (float*)d_out;

    uint16_t* xp  = (uint16_t*)d_ws;                           // 27.56 MB padded bf16 x
    uint16_t* wtb = (uint16_t*)((char*)d_ws + WT_OFF_BYTES);   // 0.59 MB bf16 weights (kt-major)

    quant_pad_x<<<NIMG * HP, 256, 0, stream>>>(x, xp);         // covers ALL of xp incl. borders
    quant_w<<<(KOUT * KK) / 256, 256, 0, stream>>>(w, wtb);

    conv_gemm<<<dim3(392), dim3(512), 0, stream>>>(xp, wtb, out);
}